// Round 4
// baseline (320.826 us; speedup 1.0000x reference)
//
#include <hip/hip_runtime.h>
#include <hip/hip_bf16.h>
#include <math.h>

// Problem constants
#define Bz 2
#define Tz 2048
#define Cz 1024
#define Hz 16
#define Dz 64      // HEAD_DIM
#define Rz 32      // ROPE_DIM
#define KVR 256
#define QR 512
#define DQK 96     // HEAD_DIM + ROPE_DIM
#define Mz (Bz*Tz)         // 4096 rows
#define BHT (Bz*Hz*Tz)     // 65536
#define QK_SCALE 0.10206207261596577f  // 1/sqrt(96)

typedef __attribute__((ext_vector_type(8))) short short8;
typedef __attribute__((ext_vector_type(4))) float f32x4;
typedef __attribute__((ext_vector_type(4))) unsigned short ushort4v;

__device__ __forceinline__ unsigned short f2bf(float f) {
    union { float f; unsigned u; } un; un.f = f;
    unsigned r = un.u + 0x7FFF + ((un.u >> 16) & 1);
    return (unsigned short)(r >> 16);
}
__device__ __forceinline__ float bf2f(unsigned short h) {
    union { unsigned u; float f; } un; un.u = ((unsigned)h) << 16; return un.f;
}

// ---------------------------------------------------------------------------
// f32 -> bf16 straight convert (n multiple of 1024)
// ---------------------------------------------------------------------------
__global__ __launch_bounds__(256) void conv_f32_bf16(const float* __restrict__ in,
                                                     unsigned short* __restrict__ out,
                                                     int n)
{
    int i = (blockIdx.x * 256 + threadIdx.x) * 4;
    if (i >= n) return;
    float4 v = *(const float4*)&in[i];
    ushort4v o = { f2bf(v.x), f2bf(v.y), f2bf(v.z), f2bf(v.w) };
    *(ushort4v*)&out[i] = o;
}

// ---------------------------------------------------------------------------
// f32 (K x N) -> bf16 transposed (N x K). 32x32 LDS tiles, both sides coalesced.
// ---------------------------------------------------------------------------
__global__ __launch_bounds__(256) void transpose_conv(const float* __restrict__ in,
                                                      unsigned short* __restrict__ out,
                                                      int K, int N)
{
    __shared__ float ts[32][33];
    int k0 = blockIdx.x * 32, n0 = blockIdx.y * 32;
    int tid = threadIdx.x;
    int r = tid >> 5, cc = tid & 31;
    #pragma unroll
    for (int l = 0; l < 4; l++)
        ts[r + l * 8][cc] = in[(size_t)(k0 + r + l * 8) * N + n0 + cc];
    __syncthreads();
    #pragma unroll
    for (int l = 0; l < 4; l++)
        out[(size_t)(n0 + r + l * 8) * K + k0 + cc] = f2bf(ts[cc][r + l * 8]);
}

// ---------------------------------------------------------------------------
// bf16 MFMA GEMM: C = A(MxK) @ W(KxN), W given TRANSPOSED (Wt is N x K).
// 64x64 tile, BK=64, 4 waves (wave w: rows w*16..+15, all 64 cols).
// amode 0: A bf16 row-major. amode 2: A bf16 heads buffer (B,H,T,64).
// omode 0: C fp32 row-major
// omode 1: C bf16 scatter (B,H,T,Dtot)+off
// omode 3: C bf16 scatter V^T (B,H,64,T)
// omode 5: C bf16 row-major
// ---------------------------------------------------------------------------
__global__ __launch_bounds__(256) void gemm_mfma(
    const unsigned short* __restrict__ A, const unsigned short* __restrict__ Wt,
    void* __restrict__ Cp, int M, int N, int K,
    int amode, int omode, int headDim, int Dtot, int off, float scale)
{
    __shared__ __attribute__((aligned(16))) unsigned short As[64 * 72];
    __shared__ __attribute__((aligned(16))) unsigned short Bs[64 * 72];

    int tid = threadIdx.x, lane = tid & 63, w = tid >> 6;
    int c = lane & 15, g = lane >> 4;
    int m0 = blockIdx.x * 64, n0 = blockIdx.y * 64;

    f32x4 acc[4] = {};

    for (int k0 = 0; k0 < K; k0 += 64) {
        #pragma unroll
        for (int l = 0; l < 2; l++) {
            int idx = tid + l * 256;
            int row = idx >> 3, c8 = idx & 7;
            const unsigned short* srcA;
            if (amode == 0) {
                srcA = &A[(size_t)(m0 + row) * K + k0 + c8 * 8];
            } else {
                int m = m0 + row;
                int b = m >> 11, t = m & (Tz - 1);
                int kk = k0 + c8 * 8;
                int h = kk >> 6, d = kk & 63;
                srcA = &A[(((size_t)b * Hz + h) * Tz + t) * 64 + d];
            }
            *(short8*)&As[row * 72 + c8 * 8] = *(const short8*)srcA;
            *(short8*)&Bs[row * 72 + c8 * 8] =
                *(const short8*)&Wt[(size_t)(n0 + row) * K + k0 + c8 * 8];
        }
        __syncthreads();

        #pragma unroll
        for (int ks = 0; ks < 64; ks += 32) {
            short8 af = *(const short8*)&As[(w * 16 + c) * 72 + ks + g * 8];
            #pragma unroll
            for (int nt = 0; nt < 4; nt++) {
                short8 bf = *(const short8*)&Bs[(nt * 16 + c) * 72 + ks + g * 8];
                acc[nt] = __builtin_amdgcn_mfma_f32_16x16x32_bf16(af, bf, acc[nt], 0, 0, 0);
            }
        }
        __syncthreads();
    }

    #pragma unroll
    for (int nt = 0; nt < 4; nt++) {
        #pragma unroll
        for (int r = 0; r < 4; r++) {
            int m = m0 + w * 16 + g * 4 + r;
            int n = n0 + nt * 16 + c;
            float v = acc[nt][r] * scale;
            if (omode == 0) {
                ((float*)Cp)[(size_t)m * N + n] = v;
            } else if (omode == 5) {
                ((unsigned short*)Cp)[(size_t)m * N + n] = f2bf(v);
            } else {
                int b = m >> 11, t = m & (Tz - 1);
                int h = n / headDim, dd = n % headDim;
                if (omode == 1)
                    ((unsigned short*)Cp)[((((size_t)b * Hz + h) * Tz + t) * Dtot) + off + dd] = f2bf(v);
                else // omode 3: V^T (B,H,64,T)
                    ((unsigned short*)Cp)[((((size_t)b * Hz + h) * 64 + dd) * Tz) + t] = f2bf(v);
            }
        }
    }
}

// ---------------------------------------------------------------------------
// RMSNorm over rows of 256: fp32 in, bf16 out, gain g. One wave per row.
// ---------------------------------------------------------------------------
__global__ __launch_bounds__(256) void rmsnorm_k(const float* __restrict__ kv,
                                                 const float* __restrict__ g,
                                                 unsigned short* __restrict__ outb)
{
    int row = blockIdx.x * 4 + (threadIdx.x >> 6);
    int lane = threadIdx.x & 63;
    const float* p = kv + (size_t)row * 256;
    float v[4];
    float ss = 0.f;
    #pragma unroll
    for (int i = 0; i < 4; i++) { v[i] = p[lane + i * 64]; ss += v[i] * v[i]; }
    #pragma unroll
    for (int o = 32; o > 0; o >>= 1) ss += __shfl_xor(ss, o);
    float r = rsqrtf(ss * (1.f / 256.f) + 1e-6f);
    #pragma unroll
    for (int i = 0; i < 4; i++)
        outb[(size_t)row * 256 + lane + i * 64] = f2bf(v[i] * r * g[lane + i * 64]);
}

// ---------------------------------------------------------------------------
// RoPE in place on the [64..96) slice of bf16 q and k (both (B,H,T,96)).
// ---------------------------------------------------------------------------
__global__ __launch_bounds__(256) void rope_bf16(unsigned short* __restrict__ qb,
                                                 unsigned short* __restrict__ kb)
{
    int idx = blockIdx.x * 256 + threadIdx.x;
    int j = idx & 15;
    int row = idx >> 4;          // 0 .. 2*BHT
    unsigned short* buf = (row >= BHT) ? kb : qb;
    if (row >= BHT) row -= BHT;
    int t = row & (Tz - 1);
    float inv = powf(10000.f, -(float)(2 * j) / 32.f);
    float ang = (float)t * inv;
    float cs = cosf(ang), sn = sinf(ang);
    unsigned short* pr = buf + (size_t)row * DQK + Dz;
    float x1 = bf2f(pr[j]), x2 = bf2f(pr[j + 16]);
    pr[j]      = f2bf(x1 * cs - x2 * sn);
    pr[j + 16] = f2bf(x2 * cs + x1 * sn);
}

// ---------------------------------------------------------------------------
// Barrier-free MFMA flash attention.
// 256 threads = 4 INDEPENDENT waves. Each wave owns one 16-row q-strip of one
// (b,h) and iterates 64-key tiles reading K and V fragments DIRECTLY from
// global (L2-resident: K+V per bh = 640 KB, 4 bh per XCD).
// Block mapping: xcd = blockIdx & 7 keeps 4 bh per XCD for L2 locality;
// strips are issued in DESCENDING work order (causal) to kill the tail.
// The only LDS is a per-wave 16x64 bf16 P-exchange strip (in-order DS ops,
// wave-private -> no __syncthreads anywhere).
// q (B,H,T,96) bf16 pre-scaled; k (B,H,T,96) bf16; vt (B,H,64,T) bf16.
// o (B,H,T,64) bf16.
// ---------------------------------------------------------------------------
#define PS_STRIDE 72

__global__ __launch_bounds__(256, 4) void attn_mfma(
    const unsigned short* __restrict__ q,
    const unsigned short* __restrict__ k,
    const unsigned short* __restrict__ vt,
    unsigned short* __restrict__ o)
{
    __shared__ __attribute__((aligned(16))) unsigned short Ps[4][16 * PS_STRIDE];

    int tid = threadIdx.x;
    int lane = tid & 63;
    int w = tid >> 6;                 // wave 0..3 (independent)
    int c = lane & 15, g = lane >> 4; // fragment coords

    // block -> (xcd, slot); 4 bh per XCD; descending-work strip order
    int blk = blockIdx.x;             // 0..1023
    int xcd = blk & 7;
    int slot = blk >> 3;              // 0..127
    int rank4 = slot >> 2;            // 0..31
    int bh = xcd * 4 + (slot & 3);    // 0..31
    int s = 127 - (rank4 * 4 + w);    // strip 0..127, longest first
    int q0 = s * 16;
    int lastkt = (s >> 2) * 64;       // last 64-key tile start

    const unsigned short* qb = q + (size_t)bh * Tz * DQK;
    const unsigned short* kb = k + (size_t)bh * Tz * DQK;
    const unsigned short* vb = vt + (size_t)bh * 64 * Tz;
    unsigned short* ps = &Ps[w][0];

    // Q fragments for this wave's strip (A-operand: row=c, k=g*8+j)
    short8 qf[3];
    {
        const unsigned short* qrow = qb + (size_t)(q0 + c) * DQK;
        #pragma unroll
        for (int kc = 0; kc < 3; kc++)
            qf[kc] = *(const short8*)(qrow + kc * 32 + g * 8);
    }

    f32x4 oacc[4] = {};
    float mrun[4], lrun[4];
    #pragma unroll
    for (int r = 0; r < 4; r++) { mrun[r] = -1e30f; lrun[r] = 0.f; }

    for (int kt0 = 0; kt0 <= lastkt; kt0 += 64) {
        // S = Q @ K^T : K B-fragments straight from global (L2)
        f32x4 sacc[4] = {};
        #pragma unroll
        for (int kc = 0; kc < 3; kc++) {
            short8 kf[4];
            #pragma unroll
            for (int nt = 0; nt < 4; nt++)
                kf[nt] = *(const short8*)&kb[(size_t)(kt0 + nt * 16 + c) * DQK + kc * 32 + g * 8];
            #pragma unroll
            for (int nt = 0; nt < 4; nt++)
                sacc[nt] = __builtin_amdgcn_mfma_f32_16x16x32_bf16(qf[kc], kf[nt], sacc[nt], 0, 0, 0);
        }

        // causal mask (only possible on the last tile)
        if (kt0 == lastkt) {
            #pragma unroll
            for (int nt = 0; nt < 4; nt++)
                #pragma unroll
                for (int r = 0; r < 4; r++)
                    if (kt0 + nt * 16 + c > q0 + g * 4 + r)
                        sacc[nt][r] = -1e30f;
        }

        // online softmax (lane's 4 q-rows; reduce across the 16 c-lanes)
        float pm[4], sc[4], rs[4];
        #pragma unroll
        for (int r = 0; r < 4; r++)
            pm[r] = fmaxf(fmaxf(sacc[0][r], sacc[1][r]), fmaxf(sacc[2][r], sacc[3][r]));
        #pragma unroll
        for (int r = 0; r < 4; r++) {
            #pragma unroll
            for (int off = 1; off < 16; off <<= 1)
                pm[r] = fmaxf(pm[r], __shfl_xor(pm[r], off));
        }
        #pragma unroll
        for (int r = 0; r < 4; r++) {
            float mn = fmaxf(mrun[r], pm[r]);
            sc[r] = __expf(mrun[r] - mn);
            mrun[r] = mn;
        }
        #pragma unroll
        for (int nt = 0; nt < 4; nt++)
            #pragma unroll
            for (int r = 0; r < 4; r++)
                sacc[nt][r] = __expf(sacc[nt][r] - mrun[r]);   // P in place
        #pragma unroll
        for (int r = 0; r < 4; r++)
            rs[r] = sacc[0][r] + sacc[1][r] + sacc[2][r] + sacc[3][r];
        #pragma unroll
        for (int r = 0; r < 4; r++) {
            #pragma unroll
            for (int off = 1; off < 16; off <<= 1)
                rs[r] += __shfl_xor(rs[r], off);
            lrun[r] = lrun[r] * sc[r] + rs[r];
        }
        #pragma unroll
        for (int nt = 0; nt < 4; nt++)
            #pragma unroll
            for (int r = 0; r < 4; r++)
                oacc[nt][r] *= sc[r];

        // P -> wave-private LDS strip (bf16), then read back as A-fragments.
        // Same-wave DS ops complete in order; wave_barrier pins compile order.
        #pragma unroll
        for (int nt = 0; nt < 4; nt++)
            #pragma unroll
            for (int r = 0; r < 4; r++)
                ps[(g * 4 + r) * PS_STRIDE + nt * 16 + c] = f2bf(sacc[nt][r]);
        __builtin_amdgcn_wave_barrier();

        // O += P @ V : V B-fragments straight from global (L2)
        #pragma unroll
        for (int kc2 = 0; kc2 < 2; kc2++) {
            short8 pf = *(const short8*)&ps[c * PS_STRIDE + kc2 * 32 + g * 8];
            short8 vf[4];
            #pragma unroll
            for (int nt = 0; nt < 4; nt++)
                vf[nt] = *(const short8*)&vb[(size_t)(nt * 16 + c) * Tz + kt0 + kc2 * 32 + g * 8];
            #pragma unroll
            for (int nt = 0; nt < 4; nt++)
                oacc[nt] = __builtin_amdgcn_mfma_f32_16x16x32_bf16(pf, vf[nt], oacc[nt], 0, 0, 0);
        }
        __builtin_amdgcn_wave_barrier();
    }

    // epilogue
    #pragma unroll
    for (int nt = 0; nt < 4; nt++)
        #pragma unroll
        for (int r = 0; r < 4; r++)
            o[((size_t)bh * Tz + q0 + g * 4 + r) * 64 + nt * 16 + c] =
                f2bf(oacc[nt][r] / lrun[r]);
}

// ---------------------------------------------------------------------------
extern "C" void kernel_launch(void* const* d_in, const int* in_sizes, int n_in,
                              void* d_out, int out_size, void* d_ws, size_t ws_size,
                              hipStream_t stream)
{
    const float* x       = (const float*)d_in[0];
    const float* W_kv    = (const float*)d_in[1];
    const float* g_kv    = (const float*)d_in[2];
    const float* W_kdec  = (const float*)d_in[3];
    const float* W_vdec  = (const float*)d_in[4];
    const float* W_q     = (const float*)d_in[5];
    const float* W_qdec  = (const float*)d_in[6];
    const float* W_krope = (const float*)d_in[7];
    const float* W_qrope = (const float*)d_in[8];
    const float* W_o     = (const float*)d_in[9];
    float* out = (float*)d_out;

    float* kv_f32 = (float*)d_ws;                           // 4096*256 f32
    unsigned short* us = (unsigned short*)(kv_f32 + (size_t)Mz * KVR);
    unsigned short* x_bf  = us;               us += (size_t)Mz * Cz;
    unsigned short* kv_bf = us;               us += (size_t)Mz * KVR;
    unsigned short* qc_bf = us;               us += (size_t)Mz * QR;
    unsigned short* qbb   = us;               us += (size_t)BHT * DQK;
    unsigned short* kbb   = us;               us += (size_t)BHT * DQK;
    unsigned short* vtb   = us;               us += (size_t)BHT * 64;
    unsigned short* ob    = us;               us += (size_t)BHT * 64;
    unsigned short* wkvT  = us;               us += (size_t)KVR * Cz;
    unsigned short* wqT   = us;               us += (size_t)QR * Cz;
    unsigned short* wkdT  = us;               us += (size_t)(Hz*Dz) * KVR;
    unsigned short* wvdT  = us;               us += (size_t)(Hz*Dz) * KVR;
    unsigned short* wqdT  = us;               us += (size_t)(Hz*Dz) * QR;
    unsigned short* wkrT  = us;               us += (size_t)(Hz*Rz) * Cz;
    unsigned short* wqrT  = us;               us += (size_t)(Hz*Rz) * QR;
    unsigned short* woT   = us;               us += (size_t)Cz * Cz;

    dim3 blk(256);

    // Converts
    conv_f32_bf16<<<dim3((Mz*Cz)/1024), blk, 0, stream>>>(x, x_bf, Mz*Cz);
    transpose_conv<<<dim3(Cz/32, KVR/32), blk, 0, stream>>>(W_kv,    wkvT, Cz,  KVR);
    transpose_conv<<<dim3(Cz/32, QR/32),  blk, 0, stream>>>(W_q,     wqT,  Cz,  QR);
    transpose_conv<<<dim3(KVR/32, (Hz*Dz)/32), blk, 0, stream>>>(W_kdec, wkdT, KVR, Hz*Dz);
    transpose_conv<<<dim3(KVR/32, (Hz*Dz)/32), blk, 0, stream>>>(W_vdec, wvdT, KVR, Hz*Dz);
    transpose_conv<<<dim3(QR/32, (Hz*Dz)/32),  blk, 0, stream>>>(W_qdec, wqdT, QR,  Hz*Dz);
    transpose_conv<<<dim3(Cz/32, (Hz*Rz)/32),  blk, 0, stream>>>(W_krope, wkrT, Cz, Hz*Rz);
    transpose_conv<<<dim3(QR/32, (Hz*Rz)/32),  blk, 0, stream>>>(W_qrope, wqrT, QR, Hz*Rz);
    transpose_conv<<<dim3(Cz/32, Cz/32),       blk, 0, stream>>>(W_o,    woT,  Cz,  Cz);

    // kv_c = x @ W_kv (fp32 out for RMSNorm)
    gemm_mfma<<<dim3(Mz/64, KVR/64), blk, 0, stream>>>(x_bf, wkvT, kv_f32, Mz, KVR, Cz, 0, 0, 0, 0, 0, 1.f);
    // RMSNorm -> bf16
    rmsnorm_k<<<dim3(Mz/4), blk, 0, stream>>>(kv_f32, g_kv, kv_bf);
    // q_c = x @ W_q (bf16 row-major)
    gemm_mfma<<<dim3(Mz/64, QR/64), blk, 0, stream>>>(x_bf, wqT, qc_bf, Mz, QR, Cz, 0, 5, 0, 0, 0, 1.f);
    // k_content -> kbb[...,0:64]
    gemm_mfma<<<dim3(Mz/64, (Hz*Dz)/64), blk, 0, stream>>>(kv_bf, wkdT, kbb, Mz, Hz*Dz, KVR, 0, 1, 64, DQK, 0, 1.f);
    // v -> vtb (B,H,64,T)
    gemm_mfma<<<dim3(Mz/64, (Hz*Dz)/64), blk, 0, stream>>>(kv_bf, wvdT, vtb, Mz, Hz*Dz, KVR, 0, 3, 64, 0, 0, 1.f);
    // q_content -> qbb[...,0:64], pre-scaled
    gemm_mfma<<<dim3(Mz/64, (Hz*Dz)/64), blk, 0, stream>>>(qc_bf, wqdT, qbb, Mz, Hz*Dz, QR, 0, 1, 64, DQK, 0, QK_SCALE);
    // k_rope -> kbb[...,64:96]
    gemm_mfma<<<dim3(Mz/64, (Hz*Rz)/64), blk, 0, stream>>>(x_bf, wkrT, kbb, Mz, Hz*Rz, Cz, 0, 1, 32, DQK, 64, 1.f);
    // q_rope -> qbb[...,64:96], pre-scaled
    gemm_mfma<<<dim3(Mz/64, (Hz*Rz)/64), blk, 0, stream>>>(qc_bf, wqrT, qbb, Mz, Hz*Rz, QR, 0, 1, 32, DQK, 64, QK_SCALE);
    // RoPE in place
    rope_bf16<<<dim3((2 * BHT * 16) / 256), blk, 0, stream>>>(qbb, kbb);
    // Barrier-free MFMA flash attention -> bf16 heads buffer
    attn_mfma<<<dim3(1024), blk, 0, stream>>>(qbb, kbb, vtb, ob);
    // out = heads(ob) @ W_o (fp32 out)
    gemm_mfma<<<dim3(Mz/64, Cz/64), blk, 0, stream>>>(ob, woT, out, Mz, Cz, Cz, 2, 0, 0, 0, 0, 1.f);
}

// Round 5
// 260.735 us; speedup vs baseline: 1.2305x; 1.2305x over previous
//
#include <hip/hip_runtime.h>
#include <hip/hip_bf16.h>
#include <math.h>

// Problem constants
#define Bz 2
#define Tz 2048
#define Cz 1024
#define Hz 16
#define Dz 64      // HEAD_DIM
#define Rz 32      // ROPE_DIM
#define KVR 256
#define QR 512
#define DQK 96     // HEAD_DIM + ROPE_DIM
#define Mz (Bz*Tz)         // 4096 rows
#define BHT (Bz*Hz*Tz)     // 65536
#define QK_SCALE 0.10206207261596577f  // 1/sqrt(96)

typedef __attribute__((ext_vector_type(8))) short short8;
typedef __attribute__((ext_vector_type(4))) float f32x4;
typedef __attribute__((ext_vector_type(4))) unsigned short ushort4v;

__device__ __forceinline__ unsigned short f2bf(float f) {
    union { float f; unsigned u; } un; un.f = f;
    unsigned r = un.u + 0x7FFF + ((un.u >> 16) & 1);
    return (unsigned short)(r >> 16);
}
__device__ __forceinline__ float bf2f(unsigned short h) {
    union { unsigned u; float f; } un; un.u = ((unsigned)h) << 16; return un.f;
}

// ---------------------------------------------------------------------------
// f32 -> bf16 straight convert (n multiple of 1024)
// ---------------------------------------------------------------------------
__global__ __launch_bounds__(256) void conv_f32_bf16(const float* __restrict__ in,
                                                     unsigned short* __restrict__ out,
                                                     int n)
{
    int i = (blockIdx.x * 256 + threadIdx.x) * 4;
    if (i >= n) return;
    float4 v = *(const float4*)&in[i];
    ushort4v o = { f2bf(v.x), f2bf(v.y), f2bf(v.z), f2bf(v.w) };
    *(ushort4v*)&out[i] = o;
}

// ---------------------------------------------------------------------------
// f32 (K x N) -> bf16 transposed (N x K). 32x32 LDS tiles, both sides coalesced.
// ---------------------------------------------------------------------------
__global__ __launch_bounds__(256) void transpose_conv(const float* __restrict__ in,
                                                      unsigned short* __restrict__ out,
                                                      int K, int N)
{
    __shared__ float ts[32][33];
    int k0 = blockIdx.x * 32, n0 = blockIdx.y * 32;
    int tid = threadIdx.x;
    int r = tid >> 5, cc = tid & 31;
    #pragma unroll
    for (int l = 0; l < 4; l++)
        ts[r + l * 8][cc] = in[(size_t)(k0 + r + l * 8) * N + n0 + cc];
    __syncthreads();
    #pragma unroll
    for (int l = 0; l < 4; l++)
        out[(size_t)(n0 + r + l * 8) * K + k0 + cc] = f2bf(ts[cc][r + l * 8]);
}

// ---------------------------------------------------------------------------
// bf16 MFMA GEMM: C = A(MxK) @ W(KxN), W given TRANSPOSED (Wt is N x K).
// 64x64 tile, BK=64, 4 waves (wave w: rows w*16..+15, all 64 cols).
// amode 0: A bf16 row-major. amode 2: A bf16 heads buffer (B,H,T,64).
// omode 0: C fp32 row-major
// omode 1: C bf16 scatter (B,H,T,Dtot)+off
// omode 3: C bf16 scatter V^T (B,H,64,T)
// omode 5: C bf16 row-major
// ---------------------------------------------------------------------------
__global__ __launch_bounds__(256) void gemm_mfma(
    const unsigned short* __restrict__ A, const unsigned short* __restrict__ Wt,
    void* __restrict__ Cp, int M, int N, int K,
    int amode, int omode, int headDim, int Dtot, int off, float scale)
{
    __shared__ __attribute__((aligned(16))) unsigned short As[64 * 72];
    __shared__ __attribute__((aligned(16))) unsigned short Bs[64 * 72];

    int tid = threadIdx.x, lane = tid & 63, w = tid >> 6;
    int c = lane & 15, g = lane >> 4;
    int m0 = blockIdx.x * 64, n0 = blockIdx.y * 64;

    f32x4 acc[4] = {};

    for (int k0 = 0; k0 < K; k0 += 64) {
        #pragma unroll
        for (int l = 0; l < 2; l++) {
            int idx = tid + l * 256;
            int row = idx >> 3, c8 = idx & 7;
            const unsigned short* srcA;
            if (amode == 0) {
                srcA = &A[(size_t)(m0 + row) * K + k0 + c8 * 8];
            } else {
                int m = m0 + row;
                int b = m >> 11, t = m & (Tz - 1);
                int kk = k0 + c8 * 8;
                int h = kk >> 6, d = kk & 63;
                srcA = &A[(((size_t)b * Hz + h) * Tz + t) * 64 + d];
            }
            *(short8*)&As[row * 72 + c8 * 8] = *(const short8*)srcA;
            *(short8*)&Bs[row * 72 + c8 * 8] =
                *(const short8*)&Wt[(size_t)(n0 + row) * K + k0 + c8 * 8];
        }
        __syncthreads();

        #pragma unroll
        for (int ks = 0; ks < 64; ks += 32) {
            short8 af = *(const short8*)&As[(w * 16 + c) * 72 + ks + g * 8];
            #pragma unroll
            for (int nt = 0; nt < 4; nt++) {
                short8 bf = *(const short8*)&Bs[(nt * 16 + c) * 72 + ks + g * 8];
                acc[nt] = __builtin_amdgcn_mfma_f32_16x16x32_bf16(af, bf, acc[nt], 0, 0, 0);
            }
        }
        __syncthreads();
    }

    #pragma unroll
    for (int nt = 0; nt < 4; nt++) {
        #pragma unroll
        for (int r = 0; r < 4; r++) {
            int m = m0 + w * 16 + g * 4 + r;
            int n = n0 + nt * 16 + c;
            float v = acc[nt][r] * scale;
            if (omode == 0) {
                ((float*)Cp)[(size_t)m * N + n] = v;
            } else if (omode == 5) {
                ((unsigned short*)Cp)[(size_t)m * N + n] = f2bf(v);
            } else {
                int b = m >> 11, t = m & (Tz - 1);
                int h = n / headDim, dd = n % headDim;
                if (omode == 1)
                    ((unsigned short*)Cp)[((((size_t)b * Hz + h) * Tz + t) * Dtot) + off + dd] = f2bf(v);
                else // omode 3: V^T (B,H,64,T)
                    ((unsigned short*)Cp)[((((size_t)b * Hz + h) * 64 + dd) * Tz) + t] = f2bf(v);
            }
        }
    }
}

// ---------------------------------------------------------------------------
// RMSNorm over rows of 256: fp32 in, bf16 out, gain g. One wave per row.
// ---------------------------------------------------------------------------
__global__ __launch_bounds__(256) void rmsnorm_k(const float* __restrict__ kv,
                                                 const float* __restrict__ g,
                                                 unsigned short* __restrict__ outb)
{
    int row = blockIdx.x * 4 + (threadIdx.x >> 6);
    int lane = threadIdx.x & 63;
    const float* p = kv + (size_t)row * 256;
    float v[4];
    float ss = 0.f;
    #pragma unroll
    for (int i = 0; i < 4; i++) { v[i] = p[lane + i * 64]; ss += v[i] * v[i]; }
    #pragma unroll
    for (int o = 32; o > 0; o >>= 1) ss += __shfl_xor(ss, o);
    float r = rsqrtf(ss * (1.f / 256.f) + 1e-6f);
    #pragma unroll
    for (int i = 0; i < 4; i++)
        outb[(size_t)row * 256 + lane + i * 64] = f2bf(v[i] * r * g[lane + i * 64]);
}

// ---------------------------------------------------------------------------
// RoPE in place on the [64..96) slice of bf16 q and k (both (B,H,T,96)).
// ---------------------------------------------------------------------------
__global__ __launch_bounds__(256) void rope_bf16(unsigned short* __restrict__ qb,
                                                 unsigned short* __restrict__ kb)
{
    int idx = blockIdx.x * 256 + threadIdx.x;
    int j = idx & 15;
    int row = idx >> 4;          // 0 .. 2*BHT
    unsigned short* buf = (row >= BHT) ? kb : qb;
    if (row >= BHT) row -= BHT;
    int t = row & (Tz - 1);
    float inv = powf(10000.f, -(float)(2 * j) / 32.f);
    float ang = (float)t * inv;
    float cs = cosf(ang), sn = sinf(ang);
    unsigned short* pr = buf + (size_t)row * DQK + Dz;
    float x1 = bf2f(pr[j]), x2 = bf2f(pr[j + 16]);
    pr[j]      = f2bf(x1 * cs - x2 * sn);
    pr[j + 16] = f2bf(x2 * cs + x1 * sn);
}

// ---------------------------------------------------------------------------
// Pipelined MFMA flash attention (2-phase, K double-buffered in LDS).
// Block = 256 threads = 4 waves; block owns 64 q-rows (wave w: rows w*16..+15)
// of one (b,h). Per 64-key tile:
//   - next K tile prefetched global->regs during compute (latency hidden)
//   - V fragments read DIRECT from L2, issued before softmax, used in PV
//   - one __syncthreads per tile (after ds_write of next K buffer)
// Launch order: longest q-blocks first; 4 bh per XCD for L2 locality.
// q (B,H,T,96) bf16 pre-scaled; k (B,H,T,96) bf16; vt (B,H,64,T) bf16.
// o (B,H,T,64) bf16.
// ---------------------------------------------------------------------------
#define KSTR 104    // 2-way bank conflict only (free)
#define PSTR 72

__global__ __launch_bounds__(256, 3) void attn_mfma(
    const unsigned short* __restrict__ q,
    const unsigned short* __restrict__ k,
    const unsigned short* __restrict__ vt,
    unsigned short* __restrict__ o)
{
    __shared__ __attribute__((aligned(16))) unsigned short Ks[2][64 * KSTR];
    __shared__ __attribute__((aligned(16))) unsigned short Ps[4][16 * PSTR];

    int tid = threadIdx.x;
    int lane = tid & 63;
    int w = tid >> 6;
    int c = lane & 15, g = lane >> 4;

    // block -> (bh, qt): spread bh 4-per-XCD, longest q-blocks first
    int idx = blockIdx.x;                      // 0..1023
    int bh = ((idx & 7) << 2) | ((idx >> 3) & 3);
    int qt = 31 - (idx >> 5);                  // 0..31
    int q0 = qt * 64;
    int ntiles = qt + 1;

    const unsigned short* qb = q + (size_t)bh * Tz * DQK;
    const unsigned short* kb = k + (size_t)bh * Tz * DQK;
    const unsigned short* vb = vt + (size_t)bh * 64 * Tz;
    unsigned short* ps = &Ps[w][0];

    // staging geometry: 768 16B-chunks = 64 rows x 12 chunks; 3 per thread
    int srow[3], sc8[3];
    #pragma unroll
    for (int i = 0; i < 3; i++) {
        int id2 = tid + i * 256;
        srow[i] = id2 / 12; sc8[i] = id2 % 12;
    }

    // Q fragments (A-operand: row=c, k=g*8..)
    short8 qf[3];
    {
        const unsigned short* qrow = qb + (size_t)(q0 + w * 16 + c) * DQK;
        #pragma unroll
        for (int kc = 0; kc < 3; kc++)
            qf[kc] = *(const short8*)(qrow + kc * 32 + g * 8);
    }

    // stage tile 0
    short8 kreg[3];
    #pragma unroll
    for (int i = 0; i < 3; i++)
        kreg[i] = *(const short8*)&kb[(size_t)srow[i] * DQK + sc8[i] * 8];
    #pragma unroll
    for (int i = 0; i < 3; i++)
        *(short8*)&Ks[0][srow[i] * KSTR + sc8[i] * 8] = kreg[i];
    __syncthreads();

    f32x4 oacc[4] = {};
    float mrun[4], lrun[4];
    #pragma unroll
    for (int r = 0; r < 4; r++) { mrun[r] = -1e30f; lrun[r] = 0.f; }

    for (int t = 0; t < ntiles; t++) {
        int cur = t & 1;
        int kt0 = t * 64;
        bool more = (t + 1) < ntiles;

        // prefetch next K tile -> regs (latency hides under compute below)
        if (more) {
            #pragma unroll
            for (int i = 0; i < 3; i++)
                kreg[i] = *(const short8*)&kb[(size_t)(kt0 + 64 + srow[i]) * DQK + sc8[i] * 8];
        }
        // issue V fragment loads now; consumed after softmax (~400cy later)
        short8 vf[2][4];
        #pragma unroll
        for (int kc2 = 0; kc2 < 2; kc2++)
            #pragma unroll
            for (int nt = 0; nt < 4; nt++)
                vf[kc2][nt] = *(const short8*)&vb[(size_t)(nt * 16 + c) * Tz + kt0 + kc2 * 32 + g * 8];

        // S = Q @ K^T from LDS buffer
        f32x4 sacc[4] = {};
        __builtin_amdgcn_s_setprio(1);
        #pragma unroll
        for (int kc = 0; kc < 3; kc++) {
            #pragma unroll
            for (int nt = 0; nt < 4; nt++) {
                short8 bfrag = *(const short8*)&Ks[cur][(nt * 16 + c) * KSTR + kc * 32 + g * 8];
                sacc[nt] = __builtin_amdgcn_mfma_f32_16x16x32_bf16(qf[kc], bfrag, sacc[nt], 0, 0, 0);
            }
        }
        __builtin_amdgcn_s_setprio(0);

        // causal mask (diagonal tile only)
        if (kt0 == q0) {
            #pragma unroll
            for (int nt = 0; nt < 4; nt++)
                #pragma unroll
                for (int r = 0; r < 4; r++)
                    if (nt * 16 + c > w * 16 + g * 4 + r)
                        sacc[nt][r] = -1e30f;
        }

        // online softmax
        float pm[4], sc[4], rs[4];
        #pragma unroll
        for (int r = 0; r < 4; r++)
            pm[r] = fmaxf(fmaxf(sacc[0][r], sacc[1][r]), fmaxf(sacc[2][r], sacc[3][r]));
        #pragma unroll
        for (int r = 0; r < 4; r++) {
            #pragma unroll
            for (int off = 1; off < 16; off <<= 1)
                pm[r] = fmaxf(pm[r], __shfl_xor(pm[r], off));
        }
        #pragma unroll
        for (int r = 0; r < 4; r++) {
            float mn = fmaxf(mrun[r], pm[r]);
            sc[r] = __expf(mrun[r] - mn);
            mrun[r] = mn;
        }
        #pragma unroll
        for (int nt = 0; nt < 4; nt++)
            #pragma unroll
            for (int r = 0; r < 4; r++)
                sacc[nt][r] = __expf(sacc[nt][r] - mrun[r]);   // P in place
        #pragma unroll
        for (int r = 0; r < 4; r++)
            rs[r] = sacc[0][r] + sacc[1][r] + sacc[2][r] + sacc[3][r];
        #pragma unroll
        for (int r = 0; r < 4; r++) {
            #pragma unroll
            for (int off = 1; off < 16; off <<= 1)
                rs[r] += __shfl_xor(rs[r], off);
            lrun[r] = lrun[r] * sc[r] + rs[r];
        }
        #pragma unroll
        for (int nt = 0; nt < 4; nt++)
            #pragma unroll
            for (int r = 0; r < 4; r++)
                oacc[nt][r] *= sc[r];

        // P -> wave-private LDS strip, read back as A-fragments
        #pragma unroll
        for (int nt = 0; nt < 4; nt++)
            #pragma unroll
            for (int r = 0; r < 4; r++)
                ps[(g * 4 + r) * PSTR + nt * 16 + c] = f2bf(sacc[nt][r]);
        __builtin_amdgcn_wave_barrier();

        // O += P @ V (V fragments already in regs)
        __builtin_amdgcn_s_setprio(1);
        #pragma unroll
        for (int kc2 = 0; kc2 < 2; kc2++) {
            short8 pf = *(const short8*)&ps[c * PSTR + kc2 * 32 + g * 8];
            #pragma unroll
            for (int nt = 0; nt < 4; nt++)
                oacc[nt] = __builtin_amdgcn_mfma_f32_16x16x32_bf16(pf, vf[kc2][nt], oacc[nt], 0, 0, 0);
        }
        __builtin_amdgcn_s_setprio(0);
        __builtin_amdgcn_wave_barrier();

        // write next K buffer, one barrier per tile
        if (more) {
            #pragma unroll
            for (int i = 0; i < 3; i++)
                *(short8*)&Ks[1 - cur][srow[i] * KSTR + sc8[i] * 8] = kreg[i];
            __syncthreads();
        }
    }

    // epilogue
    #pragma unroll
    for (int nt = 0; nt < 4; nt++)
        #pragma unroll
        for (int r = 0; r < 4; r++)
            o[((size_t)bh * Tz + q0 + w * 16 + g * 4 + r) * 64 + nt * 16 + c] =
                f2bf(oacc[nt][r] / lrun[r]);
}

// ---------------------------------------------------------------------------
extern "C" void kernel_launch(void* const* d_in, const int* in_sizes, int n_in,
                              void* d_out, int out_size, void* d_ws, size_t ws_size,
                              hipStream_t stream)
{
    const float* x       = (const float*)d_in[0];
    const float* W_kv    = (const float*)d_in[1];
    const float* g_kv    = (const float*)d_in[2];
    const float* W_kdec  = (const float*)d_in[3];
    const float* W_vdec  = (const float*)d_in[4];
    const float* W_q     = (const float*)d_in[5];
    const float* W_qdec  = (const float*)d_in[6];
    const float* W_krope = (const float*)d_in[7];
    const float* W_qrope = (const float*)d_in[8];
    const float* W_o     = (const float*)d_in[9];
    float* out = (float*)d_out;

    float* kv_f32 = (float*)d_ws;                           // 4096*256 f32
    unsigned short* us = (unsigned short*)(kv_f32 + (size_t)Mz * KVR);
    unsigned short* x_bf  = us;               us += (size_t)Mz * Cz;
    unsigned short* kv_bf = us;               us += (size_t)Mz * KVR;
    unsigned short* qc_bf = us;               us += (size_t)Mz * QR;
    unsigned short* qbb   = us;               us += (size_t)BHT * DQK;
    unsigned short* kbb   = us;               us += (size_t)BHT * DQK;
    unsigned short* vtb   = us;               us += (size_t)BHT * 64;
    unsigned short* ob    = us;               us += (size_t)BHT * 64;
    unsigned short* wkvT  = us;               us += (size_t)KVR * Cz;
    unsigned short* wqT   = us;               us += (size_t)QR * Cz;
    unsigned short* wkdT  = us;               us += (size_t)(Hz*Dz) * KVR;
    unsigned short* wvdT  = us;               us += (size_t)(Hz*Dz) * KVR;
    unsigned short* wqdT  = us;               us += (size_t)(Hz*Dz) * QR;
    unsigned short* wkrT  = us;               us += (size_t)(Hz*Rz) * Cz;
    unsigned short* wqrT  = us;               us += (size_t)(Hz*Rz) * QR;
    unsigned short* woT   = us;               us += (size_t)Cz * Cz;

    dim3 blk(256);

    // Converts
    conv_f32_bf16<<<dim3((Mz*Cz)/1024), blk, 0, stream>>>(x, x_bf, Mz*Cz);
    transpose_conv<<<dim3(Cz/32, KVR/32), blk, 0, stream>>>(W_kv,    wkvT, Cz,  KVR);
    transpose_conv<<<dim3(Cz/32, QR/32),  blk, 0, stream>>>(W_q,     wqT,  Cz,  QR);
    transpose_conv<<<dim3(KVR/32, (Hz*Dz)/32), blk, 0, stream>>>(W_kdec, wkdT, KVR, Hz*Dz);
    transpose_conv<<<dim3(KVR/32, (Hz*Dz)/32), blk, 0, stream>>>(W_vdec, wvdT, KVR, Hz*Dz);
    transpose_conv<<<dim3(QR/32, (Hz*Dz)/32),  blk, 0, stream>>>(W_qdec, wqdT, QR,  Hz*Dz);
    transpose_conv<<<dim3(Cz/32, (Hz*Rz)/32),  blk, 0, stream>>>(W_krope, wkrT, Cz, Hz*Rz);
    transpose_conv<<<dim3(QR/32, (Hz*Rz)/32),  blk, 0, stream>>>(W_qrope, wqrT, QR, Hz*Rz);
    transpose_conv<<<dim3(Cz/32, Cz/32),       blk, 0, stream>>>(W_o,    woT,  Cz,  Cz);

    // kv_c = x @ W_kv (fp32 out for RMSNorm)
    gemm_mfma<<<dim3(Mz/64, KVR/64), blk, 0, stream>>>(x_bf, wkvT, kv_f32, Mz, KVR, Cz, 0, 0, 0, 0, 0, 1.f);
    // RMSNorm -> bf16
    rmsnorm_k<<<dim3(Mz/4), blk, 0, stream>>>(kv_f32, g_kv, kv_bf);
    // q_c = x @ W_q (bf16 row-major)
    gemm_mfma<<<dim3(Mz/64, QR/64), blk, 0, stream>>>(x_bf, wqT, qc_bf, Mz, QR, Cz, 0, 5, 0, 0, 0, 1.f);
    // k_content -> kbb[...,0:64]
    gemm_mfma<<<dim3(Mz/64, (Hz*Dz)/64), blk, 0, stream>>>(kv_bf, wkdT, kbb, Mz, Hz*Dz, KVR, 0, 1, 64, DQK, 0, 1.f);
    // v -> vtb (B,H,64,T)
    gemm_mfma<<<dim3(Mz/64, (Hz*Dz)/64), blk, 0, stream>>>(kv_bf, wvdT, vtb, Mz, Hz*Dz, KVR, 0, 3, 64, 0, 0, 1.f);
    // q_content -> qbb[...,0:64], pre-scaled
    gemm_mfma<<<dim3(Mz/64, (Hz*Dz)/64), blk, 0, stream>>>(qc_bf, wqdT, qbb, Mz, Hz*Dz, QR, 0, 1, 64, DQK, 0, QK_SCALE);
    // k_rope -> kbb[...,64:96]
    gemm_mfma<<<dim3(Mz/64, (Hz*Rz)/64), blk, 0, stream>>>(x_bf, wkrT, kbb, Mz, Hz*Rz, Cz, 0, 1, 32, DQK, 64, 1.f);
    // q_rope -> qbb[...,64:96], pre-scaled
    gemm_mfma<<<dim3(Mz/64, (Hz*Rz)/64), blk, 0, stream>>>(qc_bf, wqrT, qbb, Mz, Hz*Rz, QR, 0, 1, 32, DQK, 64, QK_SCALE);
    // RoPE in place
    rope_bf16<<<dim3((2 * BHT * 16) / 256), blk, 0, stream>>>(qbb, kbb);
    // Pipelined MFMA flash attention -> bf16 heads buffer
    attn_mfma<<<dim3(1024), blk, 0, stream>>>(qbb, kbb, vtb, ob);
    // out = heads(ob) @ W_o (fp32 out)
    gemm_mfma<<<dim3(Mz/64, Cz/64), blk, 0, stream>>>(ob, woT, out, Mz, Cz, Cz, 2, 0, 0, 0, 0, 1.f);
}